// Round 1
// baseline (5514.362 us; speedup 1.0000x reference)
//
#include <hip/hip_runtime.h>

// FILL = -(float32.max / 2)
#define FILL_F (-1.7014118346046923e38f)

// Initialize output to FILL (harness poisons d_out with 0xAA each launch).
__global__ __launch_bounds__(256) void init_fill_kernel(float* __restrict__ out, int n) {
    int i = blockIdx.x * blockDim.x + threadIdx.x;
    int p = i * 4;
    if (p + 3 < n) {
        float4 v;
        v.x = FILL_F; v.y = FILL_F; v.z = FILL_F; v.w = FILL_F;
        *reinterpret_cast<float4*>(out + p) = v;
    } else {
        for (int k = p; k < n; ++k) out[k] = FILL_F;
    }
}

// Race-safe float atomic max: both branches implement stored = max(stored, v)
// in IEEE float order (monotone, commutative), so mixed concurrent updates are safe.
__device__ __forceinline__ void atomic_max_float(float* addr, float v) {
    if (v >= 0.0f) {
        atomicMax(reinterpret_cast<int*>(addr), __float_as_int(v));
    } else {
        atomicMin(reinterpret_cast<unsigned int*>(addr), __float_as_uint(v));
    }
}

// One thread owns 4 consecutive particles; loops over all BC channels.
// Intensity loads are coalesced float4 (wave reads 1 KiB contiguous per channel).
__global__ __launch_bounds__(256) void seg_max_kernel(const float* __restrict__ inten,
                                                      const int* __restrict__ pidx,
                                                      float* __restrict__ out,
                                                      int n_in, int n_out, int bc) {
    int t = blockIdx.x * blockDim.x + threadIdx.x;  // particle-quad index
    int p0 = t * 4;
    if (p0 >= n_in) return;
    const int4 idx = *reinterpret_cast<const int4*>(pidx + p0);
    for (int c = 0; c < bc; ++c) {
        const float4 v = *reinterpret_cast<const float4*>(inten + (size_t)c * n_in + p0);
        float* obase = out + (size_t)c * n_out;
        atomic_max_float(obase + idx.x, v.x);
        atomic_max_float(obase + idx.y, v.y);
        atomic_max_float(obase + idx.z, v.z);
        atomic_max_float(obase + idx.w, v.w);
    }
}

extern "C" void kernel_launch(void* const* d_in, const int* in_sizes, int n_in_arrs,
                              void* d_out, int out_size, void* d_ws, size_t ws_size,
                              hipStream_t stream) {
    const float* inten = (const float*)d_in[0];   // [B, C, N_in] fp32
    const int* pidx    = (const int*)d_in[1];     // [N_in] int32
    float* out         = (float*)d_out;           // [B, C, N_out] fp32

    const int total_in = in_sizes[0];             // B*C*N_in
    const int n_in     = in_sizes[1];             // N_in
    const int bc       = total_in / n_in;         // B*C = 64
    const int n_out    = out_size / bc;           // N_out = 262144

    const int threads = 256;

    // 1) init out to FILL
    int init_quads = (out_size + 3) / 4;
    int init_blocks = (init_quads + threads - 1) / threads;
    init_fill_kernel<<<init_blocks, threads, 0, stream>>>(out, out_size);

    // 2) scatter-max
    int quads = (n_in + 3) / 4;
    int blocks = (quads + threads - 1) / threads;
    seg_max_kernel<<<blocks, threads, 0, stream>>>(inten, pidx, out, n_in, n_out, bc);
}

// Round 2
// 2070.174 us; speedup vs baseline: 2.6637x; 2.6637x over previous
//
#include <hip/hip_runtime.h>

#define FILL_F (-1.7014118346046923e38f)

// ---- order-preserving float <-> uint key (max in uint order == max in float order)
__device__ __forceinline__ unsigned xkey(float f) {
    unsigned u = __float_as_uint(f);
    return (u & 0x80000000u) ? ~u : (u | 0x80000000u);
}
__device__ __forceinline__ float xinv(unsigned k) {
    unsigned u = (k & 0x80000000u) ? (k ^ 0x80000000u) : ~k;
    return __uint_as_float(u);
}

// ================= fallback path (round-1 kernel) =================
__global__ __launch_bounds__(256) void init_fill_kernel(float* __restrict__ out, int n) {
    int i = blockIdx.x * blockDim.x + threadIdx.x;
    int p = i * 4;
    if (p + 3 < n) {
        float4 v; v.x = FILL_F; v.y = FILL_F; v.z = FILL_F; v.w = FILL_F;
        *reinterpret_cast<float4*>(out + p) = v;
    } else {
        for (int k = p; k < n; ++k) out[k] = FILL_F;
    }
}
__device__ __forceinline__ void atomic_max_float(float* addr, float v) {
    if (v >= 0.0f) atomicMax(reinterpret_cast<int*>(addr), __float_as_int(v));
    else           atomicMin(reinterpret_cast<unsigned*>(addr), __float_as_uint(v));
}
__global__ __launch_bounds__(256) void seg_max_fallback(const float* __restrict__ inten,
                                                        const int* __restrict__ pidx,
                                                        float* __restrict__ out,
                                                        int n_in, int n_out, int bc) {
    int t = blockIdx.x * blockDim.x + threadIdx.x;
    int p0 = t * 4;
    if (p0 >= n_in) return;
    const int4 idx = *reinterpret_cast<const int4*>(pidx + p0);
    for (int c = 0; c < bc; ++c) {
        const float4 v = *reinterpret_cast<const float4*>(inten + (size_t)c * n_in + p0);
        float* obase = out + (size_t)c * n_out;
        atomic_max_float(obase + idx.x, v.x);
        atomic_max_float(obase + idx.y, v.y);
        atomic_max_float(obase + idx.z, v.z);
        atomic_max_float(obase + idx.w, v.w);
    }
}

// ================= sorted path =================
// Buckets: 2048 output slots per bucket, R = n_out/2048 buckets.
// List entry: (slot_off:11 bits << 21) | particle_id:21 bits.
#define SLOTS_PER_BUCKET 2048
#define SLOT_SHIFT 11
#define PID_BITS 21
#define PID_MASK 0x1FFFFFu
#define MAX_R 128

__global__ void zero_kernel(unsigned* a, int n) {
    int i = blockIdx.x * blockDim.x + threadIdx.x;
    if (i < n) a[i] = 0;
}

// K1: per-block LDS histogram of bucket ids, merged into global hist.
__global__ __launch_bounds__(256) void hist_kernel(const int* __restrict__ pidx, int n_in,
                                                   unsigned* __restrict__ hist, int R) {
    __shared__ unsigned lh[MAX_R];
    int tid = threadIdx.x;
    for (int i = tid; i < R; i += 256) lh[i] = 0;
    __syncthreads();
    int q = blockIdx.x * 1024 + tid;            // int4 index; block covers 4096 particles
    #pragma unroll
    for (int it = 0; it < 4; ++it) {
        int qi = q + it * 256;
        if (qi * 4 < n_in) {
            int4 s = reinterpret_cast<const int4*>(pidx)[qi];
            atomicAdd(&lh[s.x >> SLOT_SHIFT], 1u);
            atomicAdd(&lh[s.y >> SLOT_SHIFT], 1u);
            atomicAdd(&lh[s.z >> SLOT_SHIFT], 1u);
            atomicAdd(&lh[s.w >> SLOT_SHIFT], 1u);
        }
    }
    __syncthreads();
    for (int i = tid; i < R; i += 256) if (lh[i]) atomicAdd(&hist[i], lh[i]);
}

// K2: exclusive scan (R <= 128, single thread is fine) + init cursors.
__global__ void scan_kernel(const unsigned* __restrict__ hist, unsigned* __restrict__ base,
                            unsigned* __restrict__ cursor, int R) {
    if (threadIdx.x == 0 && blockIdx.x == 0) {
        unsigned acc = 0;
        for (int i = 0; i < R; ++i) { base[i] = acc; cursor[i] = acc; acc += hist[i]; }
        base[R] = acc;
    }
}

// K3: scatter packed entries into bucket lists (block-level reservation).
__global__ __launch_bounds__(256) void scatter_kernel(const int* __restrict__ pidx, int n_in,
                                                      unsigned* __restrict__ cursor,
                                                      unsigned* __restrict__ ids, int R) {
    __shared__ unsigned lcount[MAX_R], lbase[MAX_R], lcur[MAX_R];
    int tid = threadIdx.x;
    for (int i = tid; i < R; i += 256) { lcount[i] = 0; lcur[i] = 0; }
    __syncthreads();
    int q = blockIdx.x * 1024 + tid;
    int4 s[4];
    #pragma unroll
    for (int it = 0; it < 4; ++it) {
        int qi = q + it * 256;
        if (qi * 4 < n_in) {
            s[it] = reinterpret_cast<const int4*>(pidx)[qi];
            atomicAdd(&lcount[s[it].x >> SLOT_SHIFT], 1u);
            atomicAdd(&lcount[s[it].y >> SLOT_SHIFT], 1u);
            atomicAdd(&lcount[s[it].z >> SLOT_SHIFT], 1u);
            atomicAdd(&lcount[s[it].w >> SLOT_SHIFT], 1u);
        }
    }
    __syncthreads();
    for (int i = tid; i < R; i += 256) lbase[i] = atomicAdd(&cursor[i], lcount[i]);
    __syncthreads();
    #pragma unroll
    for (int it = 0; it < 4; ++it) {
        int qi = q + it * 256;
        if (qi * 4 < n_in) {
            int p0 = qi * 4;
            int sv[4] = { s[it].x, s[it].y, s[it].z, s[it].w };
            #pragma unroll
            for (int k = 0; k < 4; ++k) {
                int slot = sv[k];
                int b = slot >> SLOT_SHIFT;
                unsigned off = atomicAdd(&lcur[b], 1u);
                unsigned pack = ((unsigned)(slot & (SLOTS_PER_BUCKET - 1)) << PID_BITS) | (unsigned)(p0 + k);
                ids[lbase[b] + off] = pack;
            }
        }
    }
}

// K4: one block per (bucket, channel): LDS-accumulate 2048 slots, write once.
__global__ __launch_bounds__(256) void pool_kernel(const float* __restrict__ inten,
                                                   const unsigned* __restrict__ base,
                                                   const unsigned* __restrict__ hist,
                                                   const unsigned* __restrict__ ids,
                                                   float* __restrict__ out,
                                                   int n_in, int n_out) {
    __shared__ unsigned acc[SLOTS_PER_BUCKET];
    const int b = blockIdx.x;
    const int c = blockIdx.y;
    const int tid = threadIdx.x;
    const unsigned fillk = xkey(FILL_F);
    #pragma unroll
    for (int j = tid; j < SLOTS_PER_BUCKET; j += 256) acc[j] = fillk;
    __syncthreads();

    const unsigned beg = base[b];
    const unsigned cnt = hist[b];
    const float* __restrict__ row = inten + (size_t)c * n_in;
    const unsigned* __restrict__ lst = ids + beg;

    unsigned i = tid;
    for (; i + 768 < cnt; i += 1024) {   // 4-way MLP
        unsigned e0 = lst[i], e1 = lst[i + 256], e2 = lst[i + 512], e3 = lst[i + 768];
        float v0 = row[e0 & PID_MASK];
        float v1 = row[e1 & PID_MASK];
        float v2 = row[e2 & PID_MASK];
        float v3 = row[e3 & PID_MASK];
        atomicMax(&acc[e0 >> PID_BITS], xkey(v0));
        atomicMax(&acc[e1 >> PID_BITS], xkey(v1));
        atomicMax(&acc[e2 >> PID_BITS], xkey(v2));
        atomicMax(&acc[e3 >> PID_BITS], xkey(v3));
    }
    for (; i < cnt; i += 256) {
        unsigned e = lst[i];
        atomicMax(&acc[e >> PID_BITS], xkey(row[e & PID_MASK]));
    }
    __syncthreads();

    float* __restrict__ orow = out + (size_t)c * n_out + (size_t)b * SLOTS_PER_BUCKET;
    #pragma unroll
    for (int j = tid; j < SLOTS_PER_BUCKET; j += 256) orow[j] = xinv(acc[j]);
}

extern "C" void kernel_launch(void* const* d_in, const int* in_sizes, int n_in_arrs,
                              void* d_out, int out_size, void* d_ws, size_t ws_size,
                              hipStream_t stream) {
    const float* inten = (const float*)d_in[0];   // [B, C, N_in] fp32
    const int* pidx    = (const int*)d_in[1];     // [N_in] int32
    float* out         = (float*)d_out;           // [B, C, N_out] fp32

    const int total_in = in_sizes[0];
    const int n_in     = in_sizes[1];
    const int bc       = total_in / n_in;
    const int n_out    = out_size / bc;
    const int threads  = 256;

    const int R = n_out / SLOTS_PER_BUCKET;

    // ws layout
    size_t off_hist   = 0;
    size_t off_base   = off_hist + (size_t)MAX_R * 4;
    size_t off_cursor = off_base + (size_t)(MAX_R + 1) * 4;
    size_t off_ids    = (off_cursor + (size_t)MAX_R * 4 + 255) & ~(size_t)255;
    size_t ws_needed  = off_ids + (size_t)n_in * 4;

    bool ok = (n_out % SLOTS_PER_BUCKET == 0) && (R >= 1) && (R <= MAX_R) &&
              (n_in <= (1 << PID_BITS)) && (n_in % 4096 == 0) && (ws_size >= ws_needed);

    if (!ok) {
        int init_quads = (out_size + 3) / 4;
        init_fill_kernel<<<(init_quads + threads - 1) / threads, threads, 0, stream>>>(out, out_size);
        int quads = (n_in + 3) / 4;
        seg_max_fallback<<<(quads + threads - 1) / threads, threads, 0, stream>>>(
            inten, pidx, out, n_in, n_out, bc);
        return;
    }

    unsigned* hist   = (unsigned*)((char*)d_ws + off_hist);
    unsigned* base   = (unsigned*)((char*)d_ws + off_base);
    unsigned* cursor = (unsigned*)((char*)d_ws + off_cursor);
    unsigned* ids    = (unsigned*)((char*)d_ws + off_ids);

    zero_kernel<<<1, 256, 0, stream>>>(hist, R);

    int pblocks = n_in / 4096;
    hist_kernel<<<pblocks, threads, 0, stream>>>(pidx, n_in, hist, R);
    scan_kernel<<<1, 64, 0, stream>>>(hist, base, cursor, R);
    scatter_kernel<<<pblocks, threads, 0, stream>>>(pidx, n_in, cursor, ids, R);

    dim3 grid(R, bc);
    pool_kernel<<<grid, threads, 0, stream>>>(inten, base, hist, ids, out, n_in, n_out);
}